// Round 1
// baseline (89.381 us; speedup 1.0000x reference)
//
#include <hip/hip_runtime.h>

// Problem constants (fixed by reference setup)
#define BB    8
#define CC    96
#define NPOS  64    // PY*PX
#define JJ    17
#define KK    96
#define WIDTH 128.0f
#define GK    6     // k's per thread in pass 1
#define NG    16    // k-groups (NG*GK == KK)
#define STRIDE 66   // float2 stride per j-row in LDS (bank-conflict avoidance)
#define BLOCK 320   // 5 waves; pass1 uses JJ*NG=272 threads

__global__ __launch_bounds__(BLOCK) void pose_oks_kernel(
    const float* __restrict__ pose_pool,   // [B,C,8,8,17,2]
    const float* __restrict__ keypoints,   // [B,96,17,3]
    const float* __restrict__ areas,       // [B,96]
    const float* __restrict__ transforms,  // [B,3,3]
    const float* __restrict__ tinv,        // [B,3,3]
    const int*   __restrict__ hflip,       // [B]
    const float* __restrict__ sigmas,      // [17]
    float* __restrict__ out0,              // [B,C,64,17] oks_parts_sel
    float* __restrict__ out1,              // [B,C,64]    oks_person_sel
    float* __restrict__ out2)              // [B,C,17,3]  pose_gt
{
    const int c   = blockIdx.x;
    const int b   = blockIdx.y;
    const int tid = threadIdx.x;

    __shared__ float2 s_xy[JJ * STRIDE];   // pool coords in image space, [j][p]
    __shared__ float  s_best[JJ * KK];     // per-(j,k) best oks (vis-masked)
    __shared__ float  s_vis [JJ * KK];     // per-(j,k) vis flag
    __shared__ float  s_score[KK];
    __shared__ int    s_assign;
    __shared__ float  s_kx[JJ], s_ky[JJ], s_dnm[JJ], s_v17[JJ];

    const float ti00 = tinv[b*9+0], ti01 = tinv[b*9+1], ti02 = tinv[b*9+2];
    const float ti10 = tinv[b*9+3], ti11 = tinv[b*9+4], ti12 = tinv[b*9+5];
    const bool  flip = hflip[b] > 0;

    // ---- stage pool coords -> image coords in LDS ([j][p] layout) ----
    const float2* pp = (const float2*)(pose_pool + (size_t)(b*CC + c) * NPOS * JJ * 2);
    for (int i = tid; i < NPOS*JJ; i += BLOCK) {
        float2 v = pp[i];
        int p = i / JJ;
        int j = i - p*JJ;
        float px = flip ? (WIDTH - 1.0f - v.x) : v.x;
        float py = v.y;
        float xi = px*ti00 + py*ti01 + ti02;
        float yi = px*ti10 + py*ti11 + ti12;
        s_xy[j*STRIDE + p] = make_float2(xi, yi);
    }
    __syncthreads();

    // ---- pass 1: min squared distance over 64 positions, per (k,j) ----
    if (tid < JJ*NG) {
        const int j  = tid / NG;
        const int g  = tid - j*NG;
        const int k0 = g * GK;

        float kx[GK], ky[GK], mind[GK];
        #pragma unroll
        for (int i = 0; i < GK; i++) {
            const float* kp = keypoints + ((size_t)(b*KK + k0 + i)*JJ + j)*3;
            kx[i] = kp[0];
            ky[i] = kp[1];
            mind[i] = 3.4e38f;
        }
        for (int p = 0; p < NPOS; p++) {
            float2 xy = s_xy[j*STRIDE + p];
            #pragma unroll
            for (int i = 0; i < GK; i++) {
                float dx = xy.x - kx[i];
                float dy = xy.y - ky[i];
                float d  = dx*dx + dy*dy;
                mind[i]  = fminf(mind[i], d);
            }
        }
        const float sj   = sigmas[j];
        const float var2 = 2.0f * (2.0f*sj) * (2.0f*sj);   // 2 * (2*sigma)^2
        #pragma unroll
        for (int i = 0; i < GK; i++) {
            const int k = k0 + i;
            float kv   = keypoints[((size_t)(b*KK + k)*JJ + j)*3 + 2];
            float vf   = kv > 0.0f ? 1.0f : 0.0f;
            float dnm  = fmaxf(var2 * areas[b*KK + k], 1e-6f);
            float best = vf * expf(-mind[i] / dnm);        // max_p exp == exp(-min_p d)
            s_best[j*KK + k] = best;
            s_vis [j*KK + k] = vf;
        }
    }
    __syncthreads();

    // ---- per-k score: sum_j best / clip(sum_j vis, 1) ----
    if (tid < KK) {
        float s = 0.0f, vs = 0.0f;
        #pragma unroll
        for (int j = 0; j < JJ; j++) {
            s  += s_best[j*KK + tid];
            vs += s_vis [j*KK + tid];
        }
        s_score[tid] = s / fmaxf(vs, 1.0f);
    }
    __syncthreads();

    // ---- argmax over 96 (first-occurrence ties, like jnp.argmax) ----
    if (tid < 64) {
        float v = s_score[tid]; int bi = tid;
        if (tid < KK - 64) {
            float v2 = s_score[tid + 64];
            if (v2 > v) { v = v2; bi = tid + 64; }   // strict: keep smaller idx on tie
        }
        #pragma unroll
        for (int off = 32; off > 0; off >>= 1) {
            float ov = __shfl_xor(v, off, 64);
            int   oi = __shfl_xor(bi, off, 64);
            if (ov > v || (ov == v && oi < bi)) { v = ov; bi = oi; }
        }
        if (tid == 0) s_assign = bi;
    }
    __syncthreads();
    const int ks = s_assign;

    // ---- stage assigned GT + emit pose_gt ----
    if (tid < JJ) {
        const int j = tid;
        const float* kp = keypoints + ((size_t)(b*KK + ks)*JJ + j)*3;
        const float kx = kp[0], ky = kp[1], kv = kp[2];
        const float sj  = sigmas[j];
        const float v1  = (2.0f*sj) * (2.0f*sj);   // (2*sigma)^2
        const float area = areas[b*KK + ks];
        s_kx[j]  = kx;
        s_ky[j]  = ky;
        s_dnm[j] = fmaxf(2.0f * v1 * area, 1e-6f);
        s_v17[j] = kv > 0.0f ? 1.0f : 0.0f;

        const float* t = transforms + b*9;
        float gx = t[0]*kx + t[1]*ky + t[2];
        float gy = t[3]*kx + t[4]*ky + t[5];
        if (flip) gx = WIDTH - 1.0f - gx;
        float gv = (kv > 0.0f) ? (t[0]*t[4] * area * v1) : 0.0f;

        float* o2 = out2 + ((size_t)(b*CC + c)*JJ + j)*3;
        o2[0] = gx; o2[1] = gy; o2[2] = gv;
    }
    __syncthreads();

    // ---- pass 2: OKS maps for the assigned GT ----
    if (tid < NPOS) {
        const int p = tid;
        float sum = 0.0f, vs = 0.0f;
        float* o0 = out0 + ((size_t)(b*CC + c)*NPOS + p)*JJ;
        #pragma unroll
        for (int j = 0; j < JJ; j++) {
            float2 xy = s_xy[j*STRIDE + p];
            float dx = xy.x - s_kx[j];
            float dy = xy.y - s_ky[j];
            float d  = dx*dx + dy*dy;
            float v  = s_v17[j];
            float oks = (v > 0.0f) ? expf(-d / s_dnm[j]) : 0.0f;
            o0[j] = oks;
            sum += oks;
            vs  += v;
        }
        out1[(size_t)(b*CC + c)*NPOS + p] = sum / fmaxf(vs, 1.0f);
    }
}

extern "C" void kernel_launch(void* const* d_in, const int* in_sizes, int n_in,
                              void* d_out, int out_size, void* d_ws, size_t ws_size,
                              hipStream_t stream) {
    const float* pose_pool  = (const float*)d_in[0];
    const float* keypoints  = (const float*)d_in[1];
    const float* areas      = (const float*)d_in[2];
    const float* transforms = (const float*)d_in[3];
    const float* tinv       = (const float*)d_in[4];
    const int*   hflip      = (const int*)  d_in[5];
    const float* sigmas     = (const float*)d_in[6];
    // d_in[7]=height, d_in[8]=width — fixed at 128, hardcoded.

    float* out0 = (float*)d_out;                         // [B,C,64,17]
    float* out1 = out0 + (size_t)BB*CC*NPOS*JJ;          // [B,C,64]
    float* out2 = out1 + (size_t)BB*CC*NPOS;             // [B,C,17,3]

    dim3 grid(CC, BB);
    pose_oks_kernel<<<grid, BLOCK, 0, stream>>>(
        pose_pool, keypoints, areas, transforms, tinv, hflip, sigmas,
        out0, out1, out2);
}

// Round 2
// 88.035 us; speedup vs baseline: 1.0153x; 1.0153x over previous
//
#include <hip/hip_runtime.h>

// Problem constants (fixed by reference setup)
#define BB    8
#define CC    96
#define NPOS  64    // PY*PX
#define JJ    17
#define KK    96
#define WIDTH 128.0f
#define GK    6     // k's per thread in pass 1
#define NG    16    // k-groups (NG*GK == KK)
#define STRIDE 66   // float2 stride per j-row in LDS (bank-conflict avoidance; 66*8B = 528B, 16B-aligned rows)
#define BLOCK 320   // 5 waves; pass1 uses JJ*NG=272 threads

__global__ __launch_bounds__(BLOCK) void pose_oks_kernel(
    const float* __restrict__ pose_pool,   // [B,C,8,8,17,2]
    const float* __restrict__ keypoints,   // [B,96,17,3]
    const float* __restrict__ areas,       // [B,96]
    const float* __restrict__ transforms,  // [B,3,3]
    const float* __restrict__ tinv,        // [B,3,3]
    const int*   __restrict__ hflip,       // [B]
    const float* __restrict__ sigmas,      // [17]
    float* __restrict__ out0,              // [B,C,64,17] oks_parts_sel
    float* __restrict__ out1,              // [B,C,64]    oks_person_sel
    float* __restrict__ out2)              // [B,C,17,3]  pose_gt
{
    const int c   = blockIdx.x;
    const int b   = blockIdx.y;
    const int tid = threadIdx.x;

    __shared__ float2 s_xy[JJ * STRIDE];   // pool coords in image space, [j][p]
    __shared__ float  s_best[JJ * KK];     // per-(j,k) best oks (vis-masked)
    __shared__ float  s_vis [JJ * KK];     // per-(j,k) vis flag
    __shared__ float  s_score[KK];
    __shared__ int    s_assign;
    __shared__ float  s_kx[JJ], s_ky[JJ], s_dnm[JJ], s_v17[JJ];
    __shared__ float  s_o0[NPOS * JJ];     // pass-2 oks maps, [p][j] (contiguous for float4 store)
    __shared__ float  s_ps[4 * NPOS];      // pass-2 partial sums, [g][p]

    const float ti00 = tinv[b*9+0], ti01 = tinv[b*9+1], ti02 = tinv[b*9+2];
    const float ti10 = tinv[b*9+3], ti11 = tinv[b*9+4], ti12 = tinv[b*9+5];
    const bool  flip = hflip[b] > 0;

    // ---- stage pool coords -> image coords in LDS ([j][p] layout), float4 global loads ----
    const float4* pp4 = (const float4*)(pose_pool + (size_t)(b*CC + c) * NPOS * JJ * 2);
    for (int t = tid; t < NPOS*JJ/2; t += BLOCK) {
        float4 v = pp4[t];                 // two consecutive (p,j) float2 entries
        #pragma unroll
        for (int h = 0; h < 2; h++) {
            int i = 2*t + h;
            int p = i / JJ;
            int j = i - p*JJ;
            float vx = h ? v.z : v.x;
            float vy = h ? v.w : v.y;
            float px = flip ? (WIDTH - 1.0f - vx) : vx;
            float xi = px*ti00 + vy*ti01 + ti02;
            float yi = px*ti10 + vy*ti11 + ti12;
            s_xy[j*STRIDE + p] = make_float2(xi, yi);
        }
    }
    __syncthreads();

    // ---- pass 1: min squared distance over 64 positions, per (k,j) ----
    if (tid < JJ*NG) {
        const int j  = tid / NG;
        const int g  = tid - j*NG;
        const int k0 = g * GK;

        float kx[GK], ky[GK], mind[GK];
        #pragma unroll
        for (int i = 0; i < GK; i++) {
            const float* kp = keypoints + ((size_t)(b*KK + k0 + i)*JJ + j)*3;
            kx[i] = kp[0];
            ky[i] = kp[1];
            mind[i] = 3.4e38f;
        }
        const float4* row4 = (const float4*)(s_xy + j*STRIDE);  // 2 positions per read
        for (int t = 0; t < NPOS/2; t++) {
            float4 xy2 = row4[t];          // broadcast within j-group (same addr) -> conflict-free
            #pragma unroll
            for (int i = 0; i < GK; i++) {
                float dx0 = xy2.x - kx[i];
                float dy0 = xy2.y - ky[i];
                float d0  = dx0*dx0 + dy0*dy0;
                float dx1 = xy2.z - kx[i];
                float dy1 = xy2.w - ky[i];
                float d1  = dx1*dx1 + dy1*dy1;
                mind[i]   = fminf(mind[i], fminf(d0, d1));
            }
        }
        const float sj   = sigmas[j];
        const float var2 = 2.0f * (2.0f*sj) * (2.0f*sj);   // 2 * (2*sigma)^2
        #pragma unroll
        for (int i = 0; i < GK; i++) {
            const int k = k0 + i;
            float kv   = keypoints[((size_t)(b*KK + k)*JJ + j)*3 + 2];
            float vf   = kv > 0.0f ? 1.0f : 0.0f;
            float dnm  = fmaxf(var2 * areas[b*KK + k], 1e-6f);
            float best = vf * expf(-mind[i] / dnm);        // max_p exp == exp(-min_p d)
            s_best[j*KK + k] = best;
            s_vis [j*KK + k] = vf;
        }
    }
    __syncthreads();

    // ---- per-k score: sum_j best / clip(sum_j vis, 1) ----
    if (tid < KK) {
        float s = 0.0f, vs = 0.0f;
        #pragma unroll
        for (int j = 0; j < JJ; j++) {
            s  += s_best[j*KK + tid];
            vs += s_vis [j*KK + tid];
        }
        s_score[tid] = s / fmaxf(vs, 1.0f);
    }
    __syncthreads();

    // ---- argmax over 96 (first-occurrence ties, like jnp.argmax) ----
    if (tid < 64) {
        float v = s_score[tid]; int bi = tid;
        if (tid < KK - 64) {
            float v2 = s_score[tid + 64];
            if (v2 > v) { v = v2; bi = tid + 64; }   // strict: keep smaller idx on tie
        }
        #pragma unroll
        for (int off = 32; off > 0; off >>= 1) {
            float ov = __shfl_xor(v, off, 64);
            int   oi = __shfl_xor(bi, off, 64);
            if (ov > v || (ov == v && oi < bi)) { v = ov; bi = oi; }
        }
        if (tid == 0) s_assign = bi;
    }
    __syncthreads();
    const int ks = s_assign;

    // ---- stage assigned GT + emit pose_gt ----
    if (tid < JJ) {
        const int j = tid;
        const float* kp = keypoints + ((size_t)(b*KK + ks)*JJ + j)*3;
        const float kx = kp[0], ky = kp[1], kv = kp[2];
        const float sj  = sigmas[j];
        const float v1  = (2.0f*sj) * (2.0f*sj);   // (2*sigma)^2
        const float area = areas[b*KK + ks];
        s_kx[j]  = kx;
        s_ky[j]  = ky;
        s_dnm[j] = fmaxf(2.0f * v1 * area, 1e-6f);
        s_v17[j] = kv > 0.0f ? 1.0f : 0.0f;

        const float* t = transforms + b*9;
        float gx = t[0]*kx + t[1]*ky + t[2];
        float gy = t[3]*kx + t[4]*ky + t[5];
        if (flip) gx = WIDTH - 1.0f - gx;
        float gv = (kv > 0.0f) ? (t[0]*t[4] * area * v1) : 0.0f;

        float* o2 = out2 + ((size_t)(b*CC + c)*JJ + j)*3;
        o2[0] = gx; o2[1] = gy; o2[2] = gv;
    }
    __syncthreads();

    // ---- pass 2: OKS maps for the assigned GT, 256 threads (p × 4 j-groups) ----
    if (tid < 256) {
        const int g = tid >> 6;           // j-group 0..3
        const int p = tid & 63;
        float sum = 0.0f;
        const int nq = (g == 0) ? 5 : 4;  // g==0 also covers j=16
        for (int q = 0; q < nq; q++) {
            const int j = (q == 4) ? 16 : (g + 4*q);
            float2 xy = s_xy[j*STRIDE + p];
            float dx = xy.x - s_kx[j];
            float dy = xy.y - s_ky[j];
            float d  = dx*dx + dy*dy;
            float v  = s_v17[j];
            float oks = (v > 0.0f) ? expf(-d / s_dnm[j]) : 0.0f;
            s_o0[p*JJ + j] = oks;         // stride 17 (odd) -> conflict-free across p
            sum += oks;
        }
        s_ps[g*NPOS + p] = sum;
    }
    __syncthreads();

    // ---- coalesced out0 store (272 float4 = 1088 floats) + out1 ----
    if (tid < NPOS*JJ/4) {
        float4* dst = (float4*)(out0 + (size_t)(b*CC + c)*NPOS*JJ);
        dst[tid] = ((const float4*)s_o0)[tid];
    }
    if (tid < NPOS) {
        float vs = 0.0f;
        #pragma unroll
        for (int j = 0; j < JJ; j++) vs += s_v17[j];   // broadcast reads
        float s = s_ps[tid] + s_ps[NPOS + tid] + s_ps[2*NPOS + tid] + s_ps[3*NPOS + tid];
        out1[(size_t)(b*CC + c)*NPOS + tid] = s / fmaxf(vs, 1.0f);
    }
}

extern "C" void kernel_launch(void* const* d_in, const int* in_sizes, int n_in,
                              void* d_out, int out_size, void* d_ws, size_t ws_size,
                              hipStream_t stream) {
    const float* pose_pool  = (const float*)d_in[0];
    const float* keypoints  = (const float*)d_in[1];
    const float* areas      = (const float*)d_in[2];
    const float* transforms = (const float*)d_in[3];
    const float* tinv       = (const float*)d_in[4];
    const int*   hflip      = (const int*)  d_in[5];
    const float* sigmas     = (const float*)d_in[6];
    // d_in[7]=height, d_in[8]=width — fixed at 128, hardcoded.

    float* out0 = (float*)d_out;                         // [B,C,64,17]
    float* out1 = out0 + (size_t)BB*CC*NPOS*JJ;          // [B,C,64]
    float* out2 = out1 + (size_t)BB*CC*NPOS;             // [B,C,17,3]

    dim3 grid(CC, BB);
    pose_oks_kernel<<<grid, BLOCK, 0, stream>>>(
        pose_pool, keypoints, areas, transforms, tinv, hflip, sigmas,
        out0, out1, out2);
}